// Round 6
// baseline (3921.578 us; speedup 1.0000x reference)
//
#include <hip/hip_runtime.h>
#include <stdint.h>

#define Bsz 4096
#define Tsz 24
#define Isz 128
#define Hsz 512
#define Wsz 32
#define Msz (Bsz * Tsz)   // 98304 flat rows (b*T+t)

typedef __attribute__((ext_vector_type(8))) short short8;
typedef __attribute__((ext_vector_type(4))) float f32x4;
typedef unsigned short u16;

__device__ __forceinline__ float bf2f(u16 u) {
    union { unsigned int i; float f; } v; v.i = ((unsigned int)u) << 16; return v.f;
}
__device__ __forceinline__ u16 f2bf(float f) {
    union { float f; unsigned int i; } v; v.f = f;
    unsigned int r = v.i + 0x7fffu + ((v.i >> 16) & 1u);
    return (u16)(r >> 16);
}
__device__ __forceinline__ float sigm(float x) { return 1.0f / (1.0f + expf(-x)); }

__device__ __forceinline__ f32x4 MF(short8 a, short8 b, f32x4 c) {
    return __builtin_amdgcn_mfma_f32_16x16x32_bf16(a, b, c, 0, 0, 0);
}
__device__ __forceinline__ short8 ntload8(const u16* p) {
    return __builtin_nontemporal_load((const short8*)p);
}

#define GLOAD_LDS16(SRC, DST) \
    __builtin_amdgcn_global_load_lds( \
        (__attribute__((address_space(1))) void*)(SRC), \
        (__attribute__((address_space(3))) void*)(DST), 16, 0, 0)

// ---------------- f32 -> bf16 conversion ----------------------------------
__global__ __launch_bounds__(256) void convert_big(
    const float* __restrict__ src, u16* __restrict__ dst, int n)
{
    int i = (blockIdx.x * 256 + threadIdx.x) * 4;
    if (i + 4 <= n) {
        float4 v = *(const float4*)(src + i);
        dst[i + 0] = f2bf(v.x); dst[i + 1] = f2bf(v.y);
        dst[i + 2] = f2bf(v.z); dst[i + 3] = f2bf(v.w);
    }
}

struct ConvDesc { const float* src; u16* dst; int n; };
struct ConvTab { ConvDesc d[13]; };

__global__ __launch_bounds__(256) void convert_many(ConvTab tab)
{
    ConvDesc cd = tab.d[blockIdx.y];
    for (int i = (blockIdx.x * 256 + threadIdx.x) * 4; i < cd.n;
         i += gridDim.x * 256 * 4) {
        float4 v = *(const float4*)(cd.src + i);
        cd.dst[i + 0] = f2bf(v.x); cd.dst[i + 1] = f2bf(v.y);
        cd.dst[i + 2] = f2bf(v.z); cd.dst[i + 3] = f2bf(v.w);
    }
}

// ======================= prepass GEMM machinery (r5-exact) =================
struct Seg { const u16* A; int astr; int shift; const u16* W; int wstr; int nkb; };

__device__ __forceinline__ void stage_half(
    u16* ldsT, const u16* gbase, int rstr, int rvf,
    const u16* zerobuf, int wid, int lane)
{
#pragma unroll
    for (int q = 0; q < 4; ++q) {
        int c   = wid * 4 + q;
        int lin = c * 64 + lane;
        int row = lin >> 3;
        int gc  = lin & 7;
        const u16* src = (row >= rvf)
            ? (gbase + (long)row * rstr + ((gc ^ (row & 7)) << 3))
            : zerobuf;
        GLOAD_LDS16(src, ldsT + c * 512);
    }
}

__device__ __forceinline__ void stage_step(
    const Seg* segs, int nseg, int kb, u16* ldsA, u16* ldsB,
    int m0, int n0, const u16* zerobuf, int wid, int lane)
{
    Seg s = segs[0];
    int kloc = kb;
    if (nseg > 1 && kloc >= s.nkb) {
        kloc -= s.nkb; s = segs[1];
        if (nseg > 2 && kloc >= s.nkb) { kloc -= s.nkb; s = segs[2]; }
    }
    int base_row = m0 + s.shift;
    int rvf = base_row < 0 ? -base_row : 0;
    stage_half(ldsA, s.A + (long)base_row * s.astr + kloc * 64, s.astr, rvf,
               zerobuf, wid, lane);
    stage_half(ldsB, s.W + (long)n0 * s.wstr + kloc * 64, s.wstr, 0,
               zerobuf, wid, lane);
}

__device__ __forceinline__ void compute_tile(
    f32x4 acc[4][4], const u16* Ab, const u16* Bb, int wr, int wc, int lane)
{
    const int l15 = lane & 15;
    const int hi = lane >> 4;
#pragma unroll
    for (int ks = 0; ks < 2; ++ks) {
        int kg = ks * 4 + hi;
        short8 a[4], b[4];
#pragma unroll
        for (int am = 0; am < 4; ++am) {
            int row = wr * 64 + am * 16 + l15;
            a[am] = *(const short8*)(Ab + row * 64 + ((kg ^ (row & 7)) << 3));
        }
#pragma unroll
        for (int bn = 0; bn < 4; ++bn) {
            int row = wc * 64 + bn * 16 + l15;
            b[bn] = *(const short8*)(Bb + row * 64 + ((kg ^ (row & 7)) << 3));
        }
#pragma unroll
        for (int am = 0; am < 4; ++am)
#pragma unroll
            for (int bn = 0; bn < 4; ++bn)
                acc[am][bn] = MF(a[am], b[bn], acc[am][bn]);
    }
}

#define GEMM_CORE(SEGS, NSEG, M0, N0W)                                          \
    __shared__ u16 lds[2][2][128 * 64];                                         \
    const int lane = threadIdx.x & 63;                                          \
    const int wid  = threadIdx.x >> 6;                                          \
    const int wr = wid >> 1, wc = wid & 1;                                      \
    f32x4 acc[4][4];                                                            \
    _Pragma("unroll") for (int i_ = 0; i_ < 4; ++i_)                            \
    _Pragma("unroll") for (int j_ = 0; j_ < 4; ++j_)                            \
        acc[i_][j_] = f32x4{0, 0, 0, 0};                                        \
    int nkb = 0;                                                                \
    for (int s_ = 0; s_ < (NSEG); ++s_) nkb += (SEGS)[s_].nkb;                  \
    stage_step((SEGS), (NSEG), 0, lds[0][0], lds[0][1], (M0), (N0W),            \
               zerobuf, wid, lane);                                             \
    int cur = 0;                                                                \
    for (int kb = 0; kb < nkb; ++kb) {                                          \
        __syncthreads();                                                        \
        if (kb + 1 < nkb)                                                       \
            stage_step((SEGS), (NSEG), kb + 1, lds[cur ^ 1][0],                 \
                       lds[cur ^ 1][1], (M0), (N0W), zerobuf, wid, lane);       \
        compute_tile(acc, lds[cur][0], lds[cur][1], wr, wc, lane);              \
        cur ^= 1;                                                               \
    }

// ---------------- e = sigmoid(xw @ w_e^T + b_e), e layout [b*T+t][512] -----
__global__ __launch_bounds__(256) void ekernel(
    const u16* __restrict__ xw, const u16* __restrict__ w_e,
    const float* __restrict__ b_e, u16* __restrict__ eout)
{
    const int lane = threadIdx.x & 63;
    const int wid  = threadIdx.x >> 6;
    const int m0 = blockIdx.x * 64 + (wid >> 1) * 32;
    const int n0 = blockIdx.y * 64 + (wid & 1) * 32;
    f32x4 acc[2][2];
    acc[0][0] = f32x4{0,0,0,0}; acc[0][1] = f32x4{0,0,0,0};
    acc[1][0] = f32x4{0,0,0,0}; acc[1][1] = f32x4{0,0,0,0};
    const int l15 = lane & 15;
    const int klane = (lane >> 4) * 8;
    short8 b0 = *(const short8*)(w_e + (n0 + l15) * Wsz + klane);
    short8 b1 = *(const short8*)(w_e + (n0 + 16 + l15) * Wsz + klane);
#pragma unroll
    for (int am = 0; am < 2; ++am) {
        short8 a = *(const short8*)(xw + (long)(m0 + am * 16 + l15) * Wsz + klane);
        acc[am][0] = MF(a, b0, acc[am][0]);
        acc[am][1] = MF(a, b1, acc[am][1]);
    }
    const int col = lane & 15;
    const int r0 = (lane >> 4) * 4;
#pragma unroll
    for (int am = 0; am < 2; ++am)
#pragma unroll
        for (int bn = 0; bn < 2; ++bn)
#pragma unroll
            for (int i = 0; i < 4; ++i) {
                long row = m0 + am * 16 + r0 + i;
                int g = n0 + bn * 16 + col;
                eout[row * Hsz + g] = f2bf(sigm(acc[am][bn][i] + b_e[g]));
            }
}

// ---------------- pre-pass: writes frag-permuted prep ----------------------
// prep idx = ((((bblk*24+t)*4+gate)*16+wave)*64+lane)*16 + at*8+nt*4+i
// where b = m/24, t = m%24, bblk=b>>5, brow=b&31, at=brow>>4, hiv=(brow&15)>>2,
// iv=brow&3, lane=hiv*16+l15v, wave=colH>>5, nt=(colH&31)>>4, l15v=colH&15.
__global__ __launch_bounds__(256, 2) void prepass_kernel(
    const u16* __restrict__ x, const u16* __restrict__ e,
    const u16* __restrict__ w_d, const u16* __restrict__ w_w,
    const u16* __restrict__ w_m, const u16* __restrict__ w_rx,
    const u16* __restrict__ w_re, const u16* __restrict__ w_zx,
    const u16* __restrict__ w_ze, const u16* __restrict__ w_hx,
    const float* __restrict__ b_r, const float* __restrict__ b_z,
    const float* __restrict__ b_h,
    const u16* __restrict__ zerobuf, u16* __restrict__ prep)
{
    const int m0 = blockIdx.x * 128;
    const int y = blockIdx.y;
    const int group = y >> 2;
    const int nin = (y & 3) * 128;
    Seg segs[3];
    int nseg;
    const float* bias = nullptr;
    if (group == 0) {
        segs[0] = { x, Isz, -1 * Tsz,  w_d, Isz, Isz / 64 };
        segs[1] = { x, Isz, -7 * Tsz,  w_w, Isz, Isz / 64 };
        segs[2] = { x, Isz, -30 * Tsz, w_m, Isz, Isz / 64 };
        nseg = 3;
    } else if (group == 1) {
        segs[0] = { x, Isz, 0, w_rx, Isz, Isz / 64 };
        segs[1] = { e, Hsz, 0, w_re, Hsz, Hsz / 64 };
        nseg = 2; bias = b_r;
    } else if (group == 2) {
        segs[0] = { x, Isz, 0, w_zx, Isz, Isz / 64 };
        segs[1] = { e, Hsz, 0, w_ze, Hsz, Hsz / 64 };
        nseg = 2; bias = b_z;
    } else {
        segs[0] = { x, Isz, 0, w_hx, Isz, Isz / 64 };
        nseg = 1; bias = b_h;
    }
    GEMM_CORE(segs, nseg, m0, nin)
    const int l15 = lane & 15, hi4v = (lane >> 4) * 4;
#pragma unroll
    for (int am = 0; am < 4; ++am)
#pragma unroll
        for (int bn = 0; bn < 4; ++bn) {
            int colH = nin + wc * 64 + bn * 16 + l15;
            float bv = bias ? bias[colH] : 0.0f;
            int wv = colH >> 5, rem = colH & 31;
            int ntv = rem >> 4, l15v = rem & 15;
#pragma unroll
            for (int i = 0; i < 4; ++i) {
                long m = m0 + wr * 64 + am * 16 + hi4v + i;
                int b = (int)(m / Tsz), t = (int)(m % Tsz);
                int bblk = b >> 5, brow = b & 31;
                int atv = brow >> 4, r16 = brow & 15;
                int hiv = r16 >> 2, iv = r16 & 3;
                long idx = ((((long)(bblk * Tsz + t) * 4 + group) * 16 + wv) * 64
                            + hiv * 16 + l15v) * 16 + atv * 8 + ntv * 4 + iv;
                prep[idx] = f2bf(acc[am][bn][i] + bv);
            }
        }
}

// ======================= persistent recurrence =============================
// 128 blocks x 1024 thr (16 waves). Block owns 32 batch rows for all 24 steps.
// State in LDS (hS/hoS/rhS, XOR-swizzled, 96KB); weights L2-resident (pre/out
// use non-temporal accesses so they don't evict); pre reads are coalesced
// short8 frag loads from the permuted prep buffer.
__device__ __forceinline__ int swz(int row, int col) {
    return row * 512 + ((((col >> 3) ^ (row & 7)) << 3) | (col & 7));
}

__device__ __forceinline__ void gemm1(
    f32x4 acc[2][2], const u16* aS, const u16* __restrict__ W, int l15, int hi)
{
    const int rx = l15 & 7;
    const u16* wp = W + l15 * 512 + hi * 8;
#pragma unroll
    for (int k0 = 0; k0 < 512; k0 += 32) {
        short8 b0 = *(const short8*)(wp + k0);
        short8 b1 = *(const short8*)(wp + 16 * 512 + k0);
        const int ga = (((k0 >> 3) + hi) ^ rx) << 3;
        short8 a0 = *(const short8*)(aS + l15 * 512 + ga);
        short8 a1 = *(const short8*)(aS + (16 + l15) * 512 + ga);
        acc[0][0] = MF(a0, b0, acc[0][0]);
        acc[0][1] = MF(a0, b1, acc[0][1]);
        acc[1][0] = MF(a1, b0, acc[1][0]);
        acc[1][1] = MF(a1, b1, acc[1][1]);
    }
}

__device__ __forceinline__ void gemm2(
    f32x4 accR[2][2], f32x4 accZ[2][2], const u16* aS,
    const u16* __restrict__ WR, const u16* __restrict__ WZ, int l15, int hi)
{
    const int rx = l15 & 7;
    const u16* wpr = WR + l15 * 512 + hi * 8;
    const u16* wpz = WZ + l15 * 512 + hi * 8;
#pragma unroll
    for (int k0 = 0; k0 < 512; k0 += 32) {
        short8 r0 = *(const short8*)(wpr + k0);
        short8 r1 = *(const short8*)(wpr + 16 * 512 + k0);
        short8 z0 = *(const short8*)(wpz + k0);
        short8 z1 = *(const short8*)(wpz + 16 * 512 + k0);
        const int ga = (((k0 >> 3) + hi) ^ rx) << 3;
        short8 a0 = *(const short8*)(aS + l15 * 512 + ga);
        short8 a1 = *(const short8*)(aS + (16 + l15) * 512 + ga);
        accR[0][0] = MF(a0, r0, accR[0][0]);
        accR[0][1] = MF(a0, r1, accR[0][1]);
        accR[1][0] = MF(a1, r0, accR[1][0]);
        accR[1][1] = MF(a1, r1, accR[1][1]);
        accZ[0][0] = MF(a0, z0, accZ[0][0]);
        accZ[0][1] = MF(a0, z1, accZ[0][1]);
        accZ[1][0] = MF(a1, z0, accZ[1][0]);
        accZ[1][1] = MF(a1, z1, accZ[1][1]);
    }
}

#define FOR_FRAG \
    _Pragma("unroll") for (int at = 0; at < 2; ++at) \
    _Pragma("unroll") for (int nt = 0; nt < 2; ++nt) \
    _Pragma("unroll") for (int i = 0; i < 4; ++i)

__global__ __launch_bounds__(1024, 1) void rnn_kernel(
    const u16* __restrict__ prep, const u16* __restrict__ w_t_,
    const u16* __restrict__ w_rh, const u16* __restrict__ w_zh,
    const u16* __restrict__ w_hh, float* __restrict__ out)
{
    __shared__ __align__(16) u16 hS[32 * 512];
    __shared__ __align__(16) u16 hoS[32 * 512];
    __shared__ __align__(16) u16 rhS[32 * 512];
    const int tid = threadIdx.x;
    const int lane = tid & 63;
    const int wave = tid >> 6;
    const int l15 = lane & 15, hi = lane >> 4, hi4 = hi * 4;
    const int n0 = wave * 32;
    const long b0 = (long)blockIdx.x * 32;

    for (int i = tid * 8; i < 32 * 512; i += 1024 * 8)
        *(short8*)(hS + i) = (short8)0;
    __syncthreads();

    const u16* wT = w_t_ + (long)n0 * 512;
    const u16* wR = w_rh + (long)n0 * 512;
    const u16* wZ = w_zh + (long)n0 * 512;
    const u16* wH = w_hh + (long)n0 * 512;
    // per-thread base into the frag-permuted prep: gate g at step t lives at
    // pbase + (t*4+g)*16384
    const u16* pbase = prep + ((long)blockIdx.x * Tsz * 4) * 16384
                       + wave * 1024 + lane * 16;

#pragma unroll 1
    for (int t = 0; t < Tsz; ++t) {
        const u16* pt = pbase + (long)t * 4 * 16384;
        // prefetch gates 0..2 (o,r,z) now; gate 3 (h) before stage C
        short8 poL = ntload8(pt);
        short8 poH = ntload8(pt + 8);
        short8 prL = ntload8(pt + 16384);
        short8 prH = ntload8(pt + 16384 + 8);
        short8 pzL = ntload8(pt + 2 * 16384);
        short8 pzH = ntload8(pt + 2 * 16384 + 8);

        // ---- stage A: ho = sigm(pre_o + h @ w_t^T) ----
        f32x4 acc[2][2];
        acc[0][0] = f32x4{0,0,0,0}; acc[0][1] = f32x4{0,0,0,0};
        acc[1][0] = f32x4{0,0,0,0}; acc[1][1] = f32x4{0,0,0,0};
        gemm1(acc, hS, wT, l15, hi);
        float hov[2][2][4];
        FOR_FRAG {
            float pv = bf2f((u16)((at ? poH : poL)[nt * 4 + i]));
            float v = sigm(acc[at][nt][i] + pv);
            hov[at][nt][i] = v;
            hoS[swz(at * 16 + hi4 + i, n0 + nt * 16 + l15)] = f2bf(v);
        }
        __syncthreads();  // B1: hoS ready; hS reads (gemm1) done

        // ---- stage B: r,z = sigm(pre + ho @ w^T); rh = r*ho ----
        short8 phL = ntload8(pt + 3 * 16384);
        short8 phH = ntload8(pt + 3 * 16384 + 8);
        f32x4 accR[2][2], accZ[2][2];
        accR[0][0] = f32x4{0,0,0,0}; accR[0][1] = f32x4{0,0,0,0};
        accR[1][0] = f32x4{0,0,0,0}; accR[1][1] = f32x4{0,0,0,0};
        accZ[0][0] = f32x4{0,0,0,0}; accZ[0][1] = f32x4{0,0,0,0};
        accZ[1][0] = f32x4{0,0,0,0}; accZ[1][1] = f32x4{0,0,0,0};
        gemm2(accR, accZ, hoS, wR, wZ, l15, hi);
        float zv[2][2][4];
        FOR_FRAG {
            float pzv = bf2f((u16)((at ? pzH : pzL)[nt * 4 + i]));
            float prv = bf2f((u16)((at ? prH : prL)[nt * 4 + i]));
            zv[at][nt][i] = sigm(accZ[at][nt][i] + pzv);
            float rv = sigm(accR[at][nt][i] + prv);
            rhS[swz(at * 16 + hi4 + i, n0 + nt * 16 + l15)] =
                f2bf(rv * hov[at][nt][i]);
        }
        __syncthreads();  // B2: rhS ready; hoS reads (gemm2) done

        // ---- stage C: h~ = tanh(pre_h + rh @ w_hh^T); h = (1-z)ho + z h~ ----
        f32x4 accH[2][2];
        accH[0][0] = f32x4{0,0,0,0}; accH[0][1] = f32x4{0,0,0,0};
        accH[1][0] = f32x4{0,0,0,0}; accH[1][1] = f32x4{0,0,0,0};
        gemm1(accH, rhS, wH, l15, hi);
        FOR_FRAG {
            int row = at * 16 + hi4 + i, col = n0 + nt * 16 + l15;
            float phv = bf2f((u16)((at ? phH : phL)[nt * 4 + i]));
            float htl = tanhf(accH[at][nt][i] + phv);
            float z = zv[at][nt][i];
            float hn = (1.0f - z) * hov[at][nt][i] + z * htl;
            __builtin_nontemporal_store(
                hn, &out[((b0 + row) * Tsz + t) * (long)Hsz + col]);
            hS[swz(row, col)] = f2bf(hn);
        }
        __syncthreads();  // B3: hS ready for next step; rhS reads done
    }
}

extern "C" void kernel_launch(void* const* d_in, const int* in_sizes, int n_in,
                              void* d_out, int out_size, void* d_ws, size_t ws_size,
                              hipStream_t stream) {
    const float* x_f    = (const float*)d_in[0];
    const float* xw_f   = (const float*)d_in[1];
    const float* w_rx_f = (const float*)d_in[2];
    const float* w_rh_f = (const float*)d_in[3];
    const float* w_re_f = (const float*)d_in[4];
    const float* b_r    = (const float*)d_in[5];
    const float* w_zx_f = (const float*)d_in[6];
    const float* w_zh_f = (const float*)d_in[7];
    const float* w_ze_f = (const float*)d_in[8];
    const float* b_z    = (const float*)d_in[9];
    const float* w_hx_f = (const float*)d_in[10];
    const float* w_hh_f = (const float*)d_in[11];
    const float* b_h    = (const float*)d_in[12];
    const float* w_d_f  = (const float*)d_in[13];
    const float* w_w_f  = (const float*)d_in[14];
    const float* w_m_f  = (const float*)d_in[15];
    const float* w_t_f  = (const float*)d_in[16];
    const float* w_e_f  = (const float*)d_in[17];
    const float* b_e    = (const float*)d_in[18];
    float* out = (float*)d_out;

    char* ws = (char*)d_ws;
    size_t off = 0;
    auto alloc = [&](size_t bytes) {
        size_t o = off; off = (off + bytes + 255) & ~(size_t)255; return o;
    };
    const size_t nx  = (size_t)Msz * Isz;
    const size_t nxw = (size_t)Msz * Wsz;

    u16* x_bf  = (u16*)(ws + alloc(nx * 2));
    u16* xw_bf = (u16*)(ws + alloc(nxw * 2));
    u16* w_rx  = (u16*)(ws + alloc(Hsz * Isz * 2));
    u16* w_rh  = (u16*)(ws + alloc(Hsz * Hsz * 2));
    u16* w_re  = (u16*)(ws + alloc(Hsz * Hsz * 2));
    u16* w_zx  = (u16*)(ws + alloc(Hsz * Isz * 2));
    u16* w_zh  = (u16*)(ws + alloc(Hsz * Hsz * 2));
    u16* w_ze  = (u16*)(ws + alloc(Hsz * Hsz * 2));
    u16* w_hx  = (u16*)(ws + alloc(Hsz * Isz * 2));
    u16* w_hh  = (u16*)(ws + alloc(Hsz * Hsz * 2));
    u16* w_d   = (u16*)(ws + alloc(Hsz * Isz * 2));
    u16* w_w   = (u16*)(ws + alloc(Hsz * Isz * 2));
    u16* w_m   = (u16*)(ws + alloc(Hsz * Isz * 2));
    u16* w_t   = (u16*)(ws + alloc(Hsz * Hsz * 2));
    u16* w_e   = (u16*)(ws + alloc(Hsz * Wsz * 2));
    u16* e_bf  = (u16*)(ws + alloc((size_t)Msz * Hsz * 2));   // 96 MB [b*T+t]
    u16* prep  = (u16*)(ws + alloc((size_t)Msz * 2048 * 2));  // 384 MB permuted
    u16* zerobuf = (u16*)(ws + alloc(256));

    convert_big<<<(int)(nx / 1024), 256, 0, stream>>>(x_f, x_bf, (int)nx);
    convert_big<<<(int)(nxw / 1024), 256, 0, stream>>>(xw_f, xw_bf, (int)nxw);
    ConvTab tab;
    tab.d[0]  = { w_rx_f, w_rx, Hsz * Isz };
    tab.d[1]  = { w_rh_f, w_rh, Hsz * Hsz };
    tab.d[2]  = { w_re_f, w_re, Hsz * Hsz };
    tab.d[3]  = { w_zx_f, w_zx, Hsz * Isz };
    tab.d[4]  = { w_zh_f, w_zh, Hsz * Hsz };
    tab.d[5]  = { w_ze_f, w_ze, Hsz * Hsz };
    tab.d[6]  = { w_hx_f, w_hx, Hsz * Isz };
    tab.d[7]  = { w_hh_f, w_hh, Hsz * Hsz };
    tab.d[8]  = { w_d_f,  w_d,  Hsz * Isz };
    tab.d[9]  = { w_w_f,  w_w,  Hsz * Isz };
    tab.d[10] = { w_m_f,  w_m,  Hsz * Isz };
    tab.d[11] = { w_t_f,  w_t,  Hsz * Hsz };
    tab.d[12] = { w_e_f,  w_e,  Hsz * Wsz };
    convert_many<<<dim3(256, 13), 256, 0, stream>>>(tab);
    hipMemsetAsync(zerobuf, 0, 256, stream);

    // e = sigmoid(xw @ w_e^T + b_e)  [98304 x 512], layout [b*T+t]
    ekernel<<<dim3(Msz / 64, Hsz / 64), 256, 0, stream>>>(xw_bf, w_e, b_e, e_bf);

    // pre-pass: all input-only projections, frag-permuted output
    prepass_kernel<<<dim3(Msz / 128, 16), 256, 0, stream>>>(
        x_bf, e_bf, w_d, w_w, w_m, w_rx, w_re, w_zx, w_ze, w_hx,
        b_r, b_z, b_h, zerobuf, prep);

    // persistent recurrence: whole T-loop in one kernel
    rnn_kernel<<<Bsz / 32, 1024, 0, stream>>>(prep, w_t, w_rh, w_zh, w_hh, out);
}

// Round 7
// 3609.799 us; speedup vs baseline: 1.0864x; 1.0864x over previous
//
#include <hip/hip_runtime.h>
#include <stdint.h>

#define Bsz 4096
#define Tsz 24
#define Isz 128
#define Hsz 512
#define Wsz 32
#define Msz (Bsz * Tsz)   // 98304 flat rows (b*T+t)

typedef __attribute__((ext_vector_type(8))) short short8;
typedef __attribute__((ext_vector_type(4))) float f32x4;
typedef unsigned short u16;

__device__ __forceinline__ float bf2f(u16 u) {
    union { unsigned int i; float f; } v; v.i = ((unsigned int)u) << 16; return v.f;
}
__device__ __forceinline__ u16 f2bf(float f) {
    union { float f; unsigned int i; } v; v.f = f;
    unsigned int r = v.i + 0x7fffu + ((v.i >> 16) & 1u);
    return (u16)(r >> 16);
}
__device__ __forceinline__ float sigm(float x) { return 1.0f / (1.0f + expf(-x)); }

__device__ __forceinline__ f32x4 MF(short8 a, short8 b, f32x4 c) {
    return __builtin_amdgcn_mfma_f32_16x16x32_bf16(a, b, c, 0, 0, 0);
}

#define GLOAD_LDS16(SRC, DST) \
    __builtin_amdgcn_global_load_lds( \
        (__attribute__((address_space(1))) void*)(SRC), \
        (__attribute__((address_space(3))) void*)(DST), 16, 0, 0)

// ---------------- f32 -> bf16 conversion ----------------------------------
__global__ __launch_bounds__(256) void convert_big(
    const float* __restrict__ src, u16* __restrict__ dst, int n)
{
    int i = (blockIdx.x * 256 + threadIdx.x) * 4;
    if (i + 4 <= n) {
        float4 v = *(const float4*)(src + i);
        dst[i + 0] = f2bf(v.x); dst[i + 1] = f2bf(v.y);
        dst[i + 2] = f2bf(v.z); dst[i + 3] = f2bf(v.w);
    }
}

struct ConvDesc { const float* src; u16* dst; int n; };
struct ConvTab { ConvDesc d[13]; };

__global__ __launch_bounds__(256) void convert_many(ConvTab tab)
{
    ConvDesc cd = tab.d[blockIdx.y];
    for (int i = (blockIdx.x * 256 + threadIdx.x) * 4; i < cd.n;
         i += gridDim.x * 256 * 4) {
        float4 v = *(const float4*)(cd.src + i);
        cd.dst[i + 0] = f2bf(v.x); cd.dst[i + 1] = f2bf(v.y);
        cd.dst[i + 2] = f2bf(v.z); cd.dst[i + 3] = f2bf(v.w);
    }
}

// ======================= prepass GEMM machinery (r5-exact) =================
struct Seg { const u16* A; int astr; int shift; const u16* W; int wstr; int nkb; };

__device__ __forceinline__ void stage_half(
    u16* ldsT, const u16* gbase, int rstr, int rvf,
    const u16* zerobuf, int wid, int lane)
{
#pragma unroll
    for (int q = 0; q < 4; ++q) {
        int c   = wid * 4 + q;
        int lin = c * 64 + lane;
        int row = lin >> 3;
        int gc  = lin & 7;
        const u16* src = (row >= rvf)
            ? (gbase + (long)row * rstr + ((gc ^ (row & 7)) << 3))
            : zerobuf;
        GLOAD_LDS16(src, ldsT + c * 512);
    }
}

__device__ __forceinline__ void stage_step(
    const Seg* segs, int nseg, int kb, u16* ldsA, u16* ldsB,
    int m0, int n0, const u16* zerobuf, int wid, int lane)
{
    Seg s = segs[0];
    int kloc = kb;
    if (nseg > 1 && kloc >= s.nkb) {
        kloc -= s.nkb; s = segs[1];
        if (nseg > 2 && kloc >= s.nkb) { kloc -= s.nkb; s = segs[2]; }
    }
    int base_row = m0 + s.shift;
    int rvf = base_row < 0 ? -base_row : 0;
    stage_half(ldsA, s.A + (long)base_row * s.astr + kloc * 64, s.astr, rvf,
               zerobuf, wid, lane);
    stage_half(ldsB, s.W + (long)n0 * s.wstr + kloc * 64, s.wstr, 0,
               zerobuf, wid, lane);
}

__device__ __forceinline__ void compute_tile(
    f32x4 acc[4][4], const u16* Ab, const u16* Bb, int wr, int wc, int lane)
{
    const int l15 = lane & 15;
    const int hi = lane >> 4;
#pragma unroll
    for (int ks = 0; ks < 2; ++ks) {
        int kg = ks * 4 + hi;
        short8 a[4], b[4];
#pragma unroll
        for (int am = 0; am < 4; ++am) {
            int row = wr * 64 + am * 16 + l15;
            a[am] = *(const short8*)(Ab + row * 64 + ((kg ^ (row & 7)) << 3));
        }
#pragma unroll
        for (int bn = 0; bn < 4; ++bn) {
            int row = wc * 64 + bn * 16 + l15;
            b[bn] = *(const short8*)(Bb + row * 64 + ((kg ^ (row & 7)) << 3));
        }
#pragma unroll
        for (int am = 0; am < 4; ++am)
#pragma unroll
            for (int bn = 0; bn < 4; ++bn)
                acc[am][bn] = MF(a[am], b[bn], acc[am][bn]);
    }
}

#define GEMM_CORE(SEGS, NSEG, M0, N0W)                                          \
    __shared__ u16 lds[2][2][128 * 64];                                         \
    const int lane = threadIdx.x & 63;                                          \
    const int wid  = threadIdx.x >> 6;                                          \
    const int wr = wid >> 1, wc = wid & 1;                                      \
    f32x4 acc[4][4];                                                            \
    _Pragma("unroll") for (int i_ = 0; i_ < 4; ++i_)                            \
    _Pragma("unroll") for (int j_ = 0; j_ < 4; ++j_)                            \
        acc[i_][j_] = f32x4{0, 0, 0, 0};                                        \
    int nkb = 0;                                                                \
    for (int s_ = 0; s_ < (NSEG); ++s_) nkb += (SEGS)[s_].nkb;                  \
    stage_step((SEGS), (NSEG), 0, lds[0][0], lds[0][1], (M0), (N0W),            \
               zerobuf, wid, lane);                                             \
    int cur = 0;                                                                \
    for (int kb = 0; kb < nkb; ++kb) {                                          \
        __syncthreads();                                                        \
        if (kb + 1 < nkb)                                                       \
            stage_step((SEGS), (NSEG), kb + 1, lds[cur ^ 1][0],                 \
                       lds[cur ^ 1][1], (M0), (N0W), zerobuf, wid, lane);       \
        compute_tile(acc, lds[cur][0], lds[cur][1], wr, wc, lane);              \
        cur ^= 1;                                                               \
    }

// ---------------- e = sigmoid(xw @ w_e^T + b_e), e layout [b*T+t][512] -----
__global__ __launch_bounds__(256) void ekernel(
    const u16* __restrict__ xw, const u16* __restrict__ w_e,
    const float* __restrict__ b_e, u16* __restrict__ eout)
{
    const int lane = threadIdx.x & 63;
    const int wid  = threadIdx.x >> 6;
    const int m0 = blockIdx.x * 64 + (wid >> 1) * 32;
    const int n0 = blockIdx.y * 64 + (wid & 1) * 32;
    f32x4 acc[2][2];
    acc[0][0] = f32x4{0,0,0,0}; acc[0][1] = f32x4{0,0,0,0};
    acc[1][0] = f32x4{0,0,0,0}; acc[1][1] = f32x4{0,0,0,0};
    const int l15 = lane & 15;
    const int klane = (lane >> 4) * 8;
    short8 b0 = *(const short8*)(w_e + (n0 + l15) * Wsz + klane);
    short8 b1 = *(const short8*)(w_e + (n0 + 16 + l15) * Wsz + klane);
#pragma unroll
    for (int am = 0; am < 2; ++am) {
        short8 a = *(const short8*)(xw + (long)(m0 + am * 16 + l15) * Wsz + klane);
        acc[am][0] = MF(a, b0, acc[am][0]);
        acc[am][1] = MF(a, b1, acc[am][1]);
    }
    const int col = lane & 15;
    const int r0 = (lane >> 4) * 4;
#pragma unroll
    for (int am = 0; am < 2; ++am)
#pragma unroll
        for (int bn = 0; bn < 2; ++bn)
#pragma unroll
            for (int i = 0; i < 4; ++i) {
                long row = m0 + am * 16 + r0 + i;
                int g = n0 + bn * 16 + col;
                eout[row * Hsz + g] = f2bf(sigm(acc[am][bn][i] + b_e[g]));
            }
}

// ---------------- pre-pass: writes frag-permuted prep (r6-exact) -----------
__global__ __launch_bounds__(256, 2) void prepass_kernel(
    const u16* __restrict__ x, const u16* __restrict__ e,
    const u16* __restrict__ w_d, const u16* __restrict__ w_w,
    const u16* __restrict__ w_m, const u16* __restrict__ w_rx,
    const u16* __restrict__ w_re, const u16* __restrict__ w_zx,
    const u16* __restrict__ w_ze, const u16* __restrict__ w_hx,
    const float* __restrict__ b_r, const float* __restrict__ b_z,
    const float* __restrict__ b_h,
    const u16* __restrict__ zerobuf, u16* __restrict__ prep)
{
    const int m0 = blockIdx.x * 128;
    const int y = blockIdx.y;
    const int group = y >> 2;
    const int nin = (y & 3) * 128;
    Seg segs[3];
    int nseg;
    const float* bias = nullptr;
    if (group == 0) {
        segs[0] = { x, Isz, -1 * Tsz,  w_d, Isz, Isz / 64 };
        segs[1] = { x, Isz, -7 * Tsz,  w_w, Isz, Isz / 64 };
        segs[2] = { x, Isz, -30 * Tsz, w_m, Isz, Isz / 64 };
        nseg = 3;
    } else if (group == 1) {
        segs[0] = { x, Isz, 0, w_rx, Isz, Isz / 64 };
        segs[1] = { e, Hsz, 0, w_re, Hsz, Hsz / 64 };
        nseg = 2; bias = b_r;
    } else if (group == 2) {
        segs[0] = { x, Isz, 0, w_zx, Isz, Isz / 64 };
        segs[1] = { e, Hsz, 0, w_ze, Hsz, Hsz / 64 };
        nseg = 2; bias = b_z;
    } else {
        segs[0] = { x, Isz, 0, w_hx, Isz, Isz / 64 };
        nseg = 1; bias = b_h;
    }
    GEMM_CORE(segs, nseg, m0, nin)
    const int l15 = lane & 15, hi4v = (lane >> 4) * 4;
#pragma unroll
    for (int am = 0; am < 4; ++am)
#pragma unroll
        for (int bn = 0; bn < 4; ++bn) {
            int colH = nin + wc * 64 + bn * 16 + l15;
            float bv = bias ? bias[colH] : 0.0f;
            int wv = colH >> 5, rem = colH & 31;
            int ntv = rem >> 4, l15v = rem & 15;
#pragma unroll
            for (int i = 0; i < 4; ++i) {
                long m = m0 + wr * 64 + am * 16 + hi4v + i;
                int b = (int)(m / Tsz), t = (int)(m % Tsz);
                int bblk = b >> 5, brow = b & 31;
                int atv = brow >> 4, r16 = brow & 15;
                int hiv = r16 >> 2, iv = r16 & 3;
                long idx = ((((long)(bblk * Tsz + t) * 4 + group) * 16 + wv) * 64
                            + hiv * 16 + l15v) * 16 + atv * 8 + ntv * 4 + iv;
                prep[idx] = f2bf(acc[am][bn][i] + bv);
            }
        }
}

// ======================= persistent recurrence =============================
// 128 blocks x 1024 thr (16 waves). Block owns 32 batch rows for all 24 steps.
// State in LDS (hS + aS, 64KB); weights async-staged per wave into private
// double-buffered 2KB LDS chunks via global_load_lds + counted vmcnt (no
// barriers for weights). prep read as coalesced short8 frag loads.
__device__ __forceinline__ int swz(int row, int col) {
    return row * 512 + ((((col >> 3) ^ (row & 7)) << 3) | (col & 7));
}

// stage one k-chunk (32 k) of the wave's 32 W-rows into wave-private LDS buf
__device__ __forceinline__ void stage_w(
    const u16* __restrict__ Wm, int kc, u16* wb, int rowoff0, int rowoff1)
{
    GLOAD_LDS16(Wm + rowoff0 + kc * 32, wb);
    GLOAD_LDS16(Wm + rowoff1 + kc * 32, wb + 512);
}

// one full K=512 pass: acc += state(32 rows, LDS aS) @ Wm(32 cols)^T
__device__ __forceinline__ void wpass(
    f32x4 acc[2][2], const u16* aS, const u16* __restrict__ Wm,
    u16* wb0, u16* wb1, int rowoff0, int rowoff1, int l15, int hi)
{
    const int rx = l15 & 7;
    const int r0 = l15, r1 = 16 + l15;
    const int bo0 = (r0 * 4 + (hi ^ ((r0 >> 1) & 3))) * 8;
    const int bo1 = (r1 * 4 + (hi ^ ((r1 >> 1) & 3))) * 8;
    stage_w(Wm, 0, wb0, rowoff0, rowoff1);
#pragma unroll
    for (int kc = 0; kc < 16; ++kc) {
        if (kc < 15) {
            stage_w(Wm, kc + 1, (kc & 1) ? wb0 : wb1, rowoff0, rowoff1);
            asm volatile("s_waitcnt vmcnt(2)" ::: "memory");
        } else {
            asm volatile("s_waitcnt vmcnt(0)" ::: "memory");
        }
        const u16* cb = (kc & 1) ? wb1 : wb0;
        short8 b0 = *(const short8*)(cb + bo0);
        short8 b1 = *(const short8*)(cb + bo1);
        int ga = ((kc * 4 + hi) ^ rx) << 3;
        short8 a0 = *(const short8*)(aS + l15 * 512 + ga);
        short8 a1 = *(const short8*)(aS + (16 + l15) * 512 + ga);
        acc[0][0] = MF(a0, b0, acc[0][0]);
        acc[0][1] = MF(a0, b1, acc[0][1]);
        acc[1][0] = MF(a1, b0, acc[1][0]);
        acc[1][1] = MF(a1, b1, acc[1][1]);
    }
}

#define FOR_FRAG \
    _Pragma("unroll") for (int at = 0; at < 2; ++at) \
    _Pragma("unroll") for (int nt = 0; nt < 2; ++nt) \
    _Pragma("unroll") for (int i = 0; i < 4; ++i)

#define ZERO22(A) \
    A[0][0] = f32x4{0,0,0,0}; A[0][1] = f32x4{0,0,0,0}; \
    A[1][0] = f32x4{0,0,0,0}; A[1][1] = f32x4{0,0,0,0};

__global__ __launch_bounds__(1024, 1) void rnn_kernel(
    const u16* __restrict__ prep, const u16* __restrict__ w_t_,
    const u16* __restrict__ w_rh, const u16* __restrict__ w_zh,
    const u16* __restrict__ w_hh, float* __restrict__ out)
{
    __shared__ __align__(16) u16 hS[32 * 512];        // h state
    __shared__ __align__(16) u16 aS[32 * 512];        // ho, then rh
    __shared__ __align__(16) u16 wbuf[16][2][1024];   // per-wave weight chunks
    const int tid = threadIdx.x;
    const int lane = tid & 63;
    const int wave = tid >> 6;
    const int l15 = lane & 15, hi = lane >> 4, hi4 = hi * 4;
    const int n0 = wave * 32;
    const long b0 = (long)blockIdx.x * 32;
    u16* wb0 = &wbuf[wave][0][0];
    u16* wb1 = &wbuf[wave][1][0];

    // per-lane stage source offsets (pre-swizzled, rule #21)
    const int g0 = lane,      rs0 = g0 >> 2, ss0 = g0 & 3;
    const int g1 = 64 + lane, rs1 = g1 >> 2, ss1 = g1 & 3;
    const int rowoff0 = (n0 + rs0) * 512 + ((ss0 ^ ((rs0 >> 1) & 3)) * 8);
    const int rowoff1 = (n0 + rs1) * 512 + ((ss1 ^ ((rs1 >> 1) & 3)) * 8);

    for (int i = tid * 8; i < 32 * 512; i += 1024 * 8)
        *(short8*)(hS + i) = (short8)0;
    __syncthreads();

    const u16* pbase = prep + ((long)blockIdx.x * Tsz * 4) * 16384
                       + wave * 1024 + lane * 16;

#pragma unroll 1
    for (int t = 0; t < Tsz; ++t) {
        const u16* pt = pbase + (long)t * 4 * 16384;
        short8 poL = *(const short8*)(pt);
        short8 poH = *(const short8*)(pt + 8);

        // ---- stage A: ho = sigm(pre_o + h @ w_t^T) ----
        f32x4 acc[2][2]; ZERO22(acc)
        wpass(acc, hS, w_t_, wb0, wb1, rowoff0, rowoff1, l15, hi);
        float hov[2][2][4];
        FOR_FRAG {
            float pv = bf2f((u16)((at ? poH : poL)[nt * 4 + i]));
            float v = sigm(acc[at][nt][i] + pv);
            hov[at][nt][i] = v;
            aS[swz(at * 16 + hi4 + i, n0 + nt * 16 + l15)] = f2bf(v);
        }
        __syncthreads();  // B1: aS(=ho) ready; hS reads done

        // ---- stage B: r,z = sigm(pre + ho @ w^T); rh = r*ho ----
        short8 prL = *(const short8*)(pt + 16384);
        short8 prH = *(const short8*)(pt + 16384 + 8);
        short8 pzL = *(const short8*)(pt + 2 * 16384);
        short8 pzH = *(const short8*)(pt + 2 * 16384 + 8);
        f32x4 accR[2][2]; ZERO22(accR)
        wpass(accR, aS, w_rh, wb0, wb1, rowoff0, rowoff1, l15, hi);
        f32x4 accZ[2][2]; ZERO22(accZ)
        wpass(accZ, aS, w_zh, wb0, wb1, rowoff0, rowoff1, l15, hi);
        float zv[2][2][4], rhv[2][2][4];
        FOR_FRAG {
            float pzv = bf2f((u16)((at ? pzH : pzL)[nt * 4 + i]));
            float prv = bf2f((u16)((at ? prH : prL)[nt * 4 + i]));
            zv[at][nt][i] = sigm(accZ[at][nt][i] + pzv);
            rhv[at][nt][i] = sigm(accR[at][nt][i] + prv) * hov[at][nt][i];
        }
        __syncthreads();  // B2: all waves done READING aS(=ho)
        FOR_FRAG {
            aS[swz(at * 16 + hi4 + i, n0 + nt * 16 + l15)] = f2bf(rhv[at][nt][i]);
        }
        __syncthreads();  // B3: aS(=rh) ready

        // ---- stage C: h~ = tanh(pre_h + rh @ w_hh^T); h = (1-z)ho + z h~ ----
        short8 phL = *(const short8*)(pt + 3 * 16384);
        short8 phH = *(const short8*)(pt + 3 * 16384 + 8);
        f32x4 accH[2][2]; ZERO22(accH)
        wpass(accH, aS, w_hh, wb0, wb1, rowoff0, rowoff1, l15, hi);
        FOR_FRAG {
            int row = at * 16 + hi4 + i, col = n0 + nt * 16 + l15;
            float phv = bf2f((u16)((at ? phH : phL)[nt * 4 + i]));
            float htl = tanhf(accH[at][nt][i] + phv);
            float z = zv[at][nt][i];
            float hn = (1.0f - z) * hov[at][nt][i] + z * htl;
            out[((b0 + row) * Tsz + t) * (long)Hsz + col] = hn;
            hS[swz(row, col)] = f2bf(hn);
        }
        __syncthreads();  // B4: hS ready; aS(=rh) reads done
    }
}

extern "C" void kernel_launch(void* const* d_in, const int* in_sizes, int n_in,
                              void* d_out, int out_size, void* d_ws, size_t ws_size,
                              hipStream_t stream) {
    const float* x_f    = (const float*)d_in[0];
    const float* xw_f   = (const float*)d_in[1];
    const float* w_rx_f = (const float*)d_in[2];
    const float* w_rh_f = (const float*)d_in[3];
    const float* w_re_f = (const float*)d_in[4];
    const float* b_r    = (const float*)d_in[5];
    const float* w_zx_f = (const float*)d_in[6];
    const float* w_zh_f = (const float*)d_in[7];
    const float* w_ze_f = (const float*)d_in[8];
    const float* b_z    = (const float*)d_in[9];
    const float* w_hx_f = (const float*)d_in[10];
    const float* w_hh_f = (const float*)d_in[11];
    const float* b_h    = (const float*)d_in[12];
    const float* w_d_f  = (const float*)d_in[13];
    const float* w_w_f  = (const float*)d_in[14];
    const float* w_m_f  = (const float*)d_in[15];
    const float* w_t_f  = (const float*)d_in[16];
    const float* w_e_f  = (const float*)d_in[17];
    const float* b_e    = (const float*)d_in[18];
    float* out = (float*)d_out;

    char* ws = (char*)d_ws;
    size_t off = 0;
    auto alloc = [&](size_t bytes) {
        size_t o = off; off = (off + bytes + 255) & ~(size_t)255; return o;
    };
    const size_t nx  = (size_t)Msz * Isz;
    const size_t nxw = (size_t)Msz * Wsz;

    u16* x_bf  = (u16*)(ws + alloc(nx * 2));
    u16* xw_bf = (u16*)(ws + alloc(nxw * 2));
    u16* w_rx  = (u16*)(ws + alloc(Hsz * Isz * 2));
    u16* w_rh  = (u16*)(ws + alloc(Hsz * Hsz * 2));
    u16* w_re  = (u16*)(ws + alloc(Hsz * Hsz * 2));
    u16* w_zx  = (u16*)(ws + alloc(Hsz * Isz * 2));
    u16* w_zh  = (u16*)(ws + alloc(Hsz * Hsz * 2));
    u16* w_ze  = (u16*)(ws + alloc(Hsz * Hsz * 2));
    u16* w_hx  = (u16*)(ws + alloc(Hsz * Isz * 2));
    u16* w_hh  = (u16*)(ws + alloc(Hsz * Hsz * 2));
    u16* w_d   = (u16*)(ws + alloc(Hsz * Isz * 2));
    u16* w_w   = (u16*)(ws + alloc(Hsz * Isz * 2));
    u16* w_m   = (u16*)(ws + alloc(Hsz * Isz * 2));
    u16* w_t   = (u16*)(ws + alloc(Hsz * Hsz * 2));
    u16* w_e   = (u16*)(ws + alloc(Hsz * Wsz * 2));
    u16* e_bf  = (u16*)(ws + alloc((size_t)Msz * Hsz * 2));   // 96 MB [b*T+t]
    u16* prep  = (u16*)(ws + alloc((size_t)Msz * 2048 * 2));  // 384 MB permuted
    u16* zerobuf = (u16*)(ws + alloc(256));

    convert_big<<<(int)(nx / 1024), 256, 0, stream>>>(x_f, x_bf, (int)nx);
    convert_big<<<(int)(nxw / 1024), 256, 0, stream>>>(xw_f, xw_bf, (int)nxw);
    ConvTab tab;
    tab.d[0]  = { w_rx_f, w_rx, Hsz * Isz };
    tab.d[1]  = { w_rh_f, w_rh, Hsz * Hsz };
    tab.d[2]  = { w_re_f, w_re, Hsz * Hsz };
    tab.d[3]  = { w_zx_f, w_zx, Hsz * Isz };
    tab.d[4]  = { w_zh_f, w_zh, Hsz * Hsz };
    tab.d[5]  = { w_ze_f, w_ze, Hsz * Hsz };
    tab.d[6]  = { w_hx_f, w_hx, Hsz * Isz };
    tab.d[7]  = { w_hh_f, w_hh, Hsz * Hsz };
    tab.d[8]  = { w_d_f,  w_d,  Hsz * Isz };
    tab.d[9]  = { w_w_f,  w_w,  Hsz * Isz };
    tab.d[10] = { w_m_f,  w_m,  Hsz * Isz };
    tab.d[11] = { w_t_f,  w_t,  Hsz * Hsz };
    tab.d[12] = { w_e_f,  w_e,  Hsz * Wsz };
    convert_many<<<dim3(256, 13), 256, 0, stream>>>(tab);
    hipMemsetAsync(zerobuf, 0, 256, stream);

    // e = sigmoid(xw @ w_e^T + b_e)  [98304 x 512], layout [b*T+t]
    ekernel<<<dim3(Msz / 64, Hsz / 64), 256, 0, stream>>>(xw_bf, w_e, b_e, e_bf);

    // pre-pass: all input-only projections, frag-permuted output
    prepass_kernel<<<dim3(Msz / 128, 16), 256, 0, stream>>>(
        x_bf, e_bf, w_d, w_w, w_m, w_rx, w_re, w_zx, w_ze, w_hx,
        b_r, b_z, b_h, zerobuf, prep);

    // persistent recurrence: whole T-loop in one kernel
    rnn_kernel<<<Bsz / 32, 1024, 0, stream>>>(prep, w_t, w_rh, w_zh, w_hh, out);
}

// Round 8
// 2492.469 us; speedup vs baseline: 1.5734x; 1.4483x over previous
//
#include <hip/hip_runtime.h>
#include <stdint.h>

#define Bsz 4096
#define Tsz 24
#define Isz 128
#define Hsz 512
#define Wsz 32
#define Msz (Bsz * Tsz)   // 98304 flat rows (b*T+t)

typedef __attribute__((ext_vector_type(8))) short short8;
typedef __attribute__((ext_vector_type(4))) float f32x4;
typedef unsigned short u16;

__device__ __forceinline__ float bf2f(u16 u) {
    union { unsigned int i; float f; } v; v.i = ((unsigned int)u) << 16; return v.f;
}
__device__ __forceinline__ u16 f2bf(float f) {
    union { float f; unsigned int i; } v; v.f = f;
    unsigned int r = v.i + 0x7fffu + ((v.i >> 16) & 1u);
    return (u16)(r >> 16);
}
__device__ __forceinline__ float sigm(float x) { return 1.0f / (1.0f + expf(-x)); }

__device__ __forceinline__ f32x4 MF(short8 a, short8 b, f32x4 c) {
    return __builtin_amdgcn_mfma_f32_16x16x32_bf16(a, b, c, 0, 0, 0);
}
__device__ __forceinline__ short8 ntload8(const u16* p) {
    return __builtin_nontemporal_load((const short8*)p);
}

#define GLOAD_LDS16(SRC, DST) \
    __builtin_amdgcn_global_load_lds( \
        (__attribute__((address_space(1))) void*)(SRC), \
        (__attribute__((address_space(3))) void*)(DST), 16, 0, 0)

// ---------------- f32 -> bf16 conversion ----------------------------------
__global__ __launch_bounds__(256) void convert_big(
    const float* __restrict__ src, u16* __restrict__ dst, int n)
{
    int i = (blockIdx.x * 256 + threadIdx.x) * 4;
    if (i + 4 <= n) {
        float4 v = *(const float4*)(src + i);
        dst[i + 0] = f2bf(v.x); dst[i + 1] = f2bf(v.y);
        dst[i + 2] = f2bf(v.z); dst[i + 3] = f2bf(v.w);
    }
}

struct ConvDesc { const float* src; u16* dst; int n; };
struct ConvTab { ConvDesc d[13]; };

__global__ __launch_bounds__(256) void convert_many(ConvTab tab)
{
    ConvDesc cd = tab.d[blockIdx.y];
    for (int i = (blockIdx.x * 256 + threadIdx.x) * 4; i < cd.n;
         i += gridDim.x * 256 * 4) {
        float4 v = *(const float4*)(cd.src + i);
        cd.dst[i + 0] = f2bf(v.x); cd.dst[i + 1] = f2bf(v.y);
        cd.dst[i + 2] = f2bf(v.z); cd.dst[i + 3] = f2bf(v.w);
    }
}

// ======================= prepass GEMM machinery (r5-exact) =================
struct Seg { const u16* A; int astr; int shift; const u16* W; int wstr; int nkb; };

__device__ __forceinline__ void stage_half(
    u16* ldsT, const u16* gbase, int rstr, int rvf,
    const u16* zerobuf, int wid, int lane)
{
#pragma unroll
    for (int q = 0; q < 4; ++q) {
        int c   = wid * 4 + q;
        int lin = c * 64 + lane;
        int row = lin >> 3;
        int gc  = lin & 7;
        const u16* src = (row >= rvf)
            ? (gbase + (long)row * rstr + ((gc ^ (row & 7)) << 3))
            : zerobuf;
        GLOAD_LDS16(src, ldsT + c * 512);
    }
}

__device__ __forceinline__ void stage_step(
    const Seg* segs, int nseg, int kb, u16* ldsA, u16* ldsB,
    int m0, int n0, const u16* zerobuf, int wid, int lane)
{
    Seg s = segs[0];
    int kloc = kb;
    if (nseg > 1 && kloc >= s.nkb) {
        kloc -= s.nkb; s = segs[1];
        if (nseg > 2 && kloc >= s.nkb) { kloc -= s.nkb; s = segs[2]; }
    }
    int base_row = m0 + s.shift;
    int rvf = base_row < 0 ? -base_row : 0;
    stage_half(ldsA, s.A + (long)base_row * s.astr + kloc * 64, s.astr, rvf,
               zerobuf, wid, lane);
    stage_half(ldsB, s.W + (long)n0 * s.wstr + kloc * 64, s.wstr, 0,
               zerobuf, wid, lane);
}

__device__ __forceinline__ void compute_tile(
    f32x4 acc[4][4], const u16* Ab, const u16* Bb, int wr, int wc, int lane)
{
    const int l15 = lane & 15;
    const int hi = lane >> 4;
#pragma unroll
    for (int ks = 0; ks < 2; ++ks) {
        int kg = ks * 4 + hi;
        short8 a[4], b[4];
#pragma unroll
        for (int am = 0; am < 4; ++am) {
            int row = wr * 64 + am * 16 + l15;
            a[am] = *(const short8*)(Ab + row * 64 + ((kg ^ (row & 7)) << 3));
        }
#pragma unroll
        for (int bn = 0; bn < 4; ++bn) {
            int row = wc * 64 + bn * 16 + l15;
            b[bn] = *(const short8*)(Bb + row * 64 + ((kg ^ (row & 7)) << 3));
        }
#pragma unroll
        for (int am = 0; am < 4; ++am)
#pragma unroll
            for (int bn = 0; bn < 4; ++bn)
                acc[am][bn] = MF(a[am], b[bn], acc[am][bn]);
    }
}

#define GEMM_CORE(SEGS, NSEG, M0, N0W)                                          \
    __shared__ u16 lds[2][2][128 * 64];                                         \
    const int lane = threadIdx.x & 63;                                          \
    const int wid  = threadIdx.x >> 6;                                          \
    const int wr = wid >> 1, wc = wid & 1;                                      \
    f32x4 acc[4][4];                                                            \
    _Pragma("unroll") for (int i_ = 0; i_ < 4; ++i_)                            \
    _Pragma("unroll") for (int j_ = 0; j_ < 4; ++j_)                            \
        acc[i_][j_] = f32x4{0, 0, 0, 0};                                        \
    int nkb = 0;                                                                \
    for (int s_ = 0; s_ < (NSEG); ++s_) nkb += (SEGS)[s_].nkb;                  \
    stage_step((SEGS), (NSEG), 0, lds[0][0], lds[0][1], (M0), (N0W),            \
               zerobuf, wid, lane);                                             \
    int cur = 0;                                                                \
    for (int kb = 0; kb < nkb; ++kb) {                                          \
        __syncthreads();                                                        \
        if (kb + 1 < nkb)                                                       \
            stage_step((SEGS), (NSEG), kb + 1, lds[cur ^ 1][0],                 \
                       lds[cur ^ 1][1], (M0), (N0W), zerobuf, wid, lane);       \
        compute_tile(acc, lds[cur][0], lds[cur][1], wr, wc, lane);              \
        cur ^= 1;                                                               \
    }

// ---------------- e = sigmoid(xw @ w_e^T + b_e), e layout [b*T+t][512] -----
__global__ __launch_bounds__(256) void ekernel(
    const u16* __restrict__ xw, const u16* __restrict__ w_e,
    const float* __restrict__ b_e, u16* __restrict__ eout)
{
    const int lane = threadIdx.x & 63;
    const int wid  = threadIdx.x >> 6;
    const int m0 = blockIdx.x * 64 + (wid >> 1) * 32;
    const int n0 = blockIdx.y * 64 + (wid & 1) * 32;
    f32x4 acc[2][2];
    acc[0][0] = f32x4{0,0,0,0}; acc[0][1] = f32x4{0,0,0,0};
    acc[1][0] = f32x4{0,0,0,0}; acc[1][1] = f32x4{0,0,0,0};
    const int l15 = lane & 15;
    const int klane = (lane >> 4) * 8;
    short8 b0 = *(const short8*)(w_e + (n0 + l15) * Wsz + klane);
    short8 b1 = *(const short8*)(w_e + (n0 + 16 + l15) * Wsz + klane);
#pragma unroll
    for (int am = 0; am < 2; ++am) {
        short8 a = *(const short8*)(xw + (long)(m0 + am * 16 + l15) * Wsz + klane);
        acc[am][0] = MF(a, b0, acc[am][0]);
        acc[am][1] = MF(a, b1, acc[am][1]);
    }
    const int col = lane & 15;
    const int r0 = (lane >> 4) * 4;
#pragma unroll
    for (int am = 0; am < 2; ++am)
#pragma unroll
        for (int bn = 0; bn < 2; ++bn)
#pragma unroll
            for (int i = 0; i < 4; ++i) {
                long row = m0 + am * 16 + r0 + i;
                int g = n0 + bn * 16 + col;
                eout[row * Hsz + g] = f2bf(sigm(acc[am][bn][i] + b_e[g]));
            }
}

// ---------------- pre-pass: writes frag-permuted prep ----------------------
// New layout for 16-row / 8-wave rnn blocks:
// idx = ((((bblk*24+t)*4+gate)*8+wave)*64 + hiv*16+l15v)*16 + bnv*4 + iv
// b = m/24, t = m%24; bblk=b>>4; rowin=b&15; hiv=rowin>>2; iv=rowin&3;
// wave=colH>>6; bnv=(colH>>4)&3; l15v=colH&15.
// (verified: b=17,t=3,colH=321,gate=2 -> idx 906257 both directions)
__global__ __launch_bounds__(256, 2) void prepass_kernel(
    const u16* __restrict__ x, const u16* __restrict__ e,
    const u16* __restrict__ w_d, const u16* __restrict__ w_w,
    const u16* __restrict__ w_m, const u16* __restrict__ w_rx,
    const u16* __restrict__ w_re, const u16* __restrict__ w_zx,
    const u16* __restrict__ w_ze, const u16* __restrict__ w_hx,
    const float* __restrict__ b_r, const float* __restrict__ b_z,
    const float* __restrict__ b_h,
    const u16* __restrict__ zerobuf, u16* __restrict__ prep)
{
    const int m0 = blockIdx.x * 128;
    const int y = blockIdx.y;
    const int group = y >> 2;
    const int nin = (y & 3) * 128;
    Seg segs[3];
    int nseg;
    const float* bias = nullptr;
    if (group == 0) {
        segs[0] = { x, Isz, -1 * Tsz,  w_d, Isz, Isz / 64 };
        segs[1] = { x, Isz, -7 * Tsz,  w_w, Isz, Isz / 64 };
        segs[2] = { x, Isz, -30 * Tsz, w_m, Isz, Isz / 64 };
        nseg = 3;
    } else if (group == 1) {
        segs[0] = { x, Isz, 0, w_rx, Isz, Isz / 64 };
        segs[1] = { e, Hsz, 0, w_re, Hsz, Hsz / 64 };
        nseg = 2; bias = b_r;
    } else if (group == 2) {
        segs[0] = { x, Isz, 0, w_zx, Isz, Isz / 64 };
        segs[1] = { e, Hsz, 0, w_ze, Hsz, Hsz / 64 };
        nseg = 2; bias = b_z;
    } else {
        segs[0] = { x, Isz, 0, w_hx, Isz, Isz / 64 };
        nseg = 1; bias = b_h;
    }
    GEMM_CORE(segs, nseg, m0, nin)
    const int l15 = lane & 15, hi4v = (lane >> 4) * 4;
#pragma unroll
    for (int am = 0; am < 4; ++am)
#pragma unroll
        for (int bn = 0; bn < 4; ++bn) {
            int colH = nin + wc * 64 + bn * 16 + l15;
            float bv = bias ? bias[colH] : 0.0f;
            int wavev = colH >> 6, bnv = (colH >> 4) & 3, l15v = colH & 15;
#pragma unroll
            for (int i = 0; i < 4; ++i) {
                long m = m0 + wr * 64 + am * 16 + hi4v + i;
                int b = (int)(m / Tsz), t = (int)(m % Tsz);
                int bblk = b >> 4, rowin = b & 15;
                int hiv = rowin >> 2, iv = rowin & 3;
                long idx = ((((long)(bblk * Tsz + t) * 4 + group) * 8 + wavev) * 64
                            + hiv * 16 + l15v) * 16 + bnv * 4 + iv;
                prep[idx] = f2bf(acc[am][bn][i] + bv);
            }
        }
}

// ======================= persistent recurrence =============================
// 256 blocks x 512 thr (8 waves). Block owns 16 batch rows for all 24 steps.
// Each wave owns 64 output cols (n0 = wave*64). State (16x512) in LDS,
// XOR-granule swizzled. Weights loaded straight to registers (L2-resident —
// prep/out use non-temporal accesses so the streams don't evict them).
__device__ __forceinline__ int swz16(int row, int col) {
    return row * 512 + ((((col >> 3) ^ (row & 7)) << 3) | (col & 7));
}

// acc[bn] += state(16 x 512, LDS) @ Wm cols [n0, n0+64)
__device__ __forceinline__ void wpass1(
    f32x4 acc[4], const u16* aS, const u16* __restrict__ Wm,
    int n0, int l15, int hi)
{
    const int rx = l15 & 7;
    const u16* wp = Wm + (long)(n0 + l15) * 512 + hi * 8;
#pragma unroll 4
    for (int kc = 0; kc < 16; ++kc) {
        short8 b0 = *(const short8*)(wp + kc * 32);
        short8 b1 = *(const short8*)(wp + 16 * 512 + kc * 32);
        short8 b2 = *(const short8*)(wp + 32 * 512 + kc * 32);
        short8 b3 = *(const short8*)(wp + 48 * 512 + kc * 32);
        int ga = ((kc * 4 + hi) ^ rx) << 3;
        short8 a = *(const short8*)(aS + l15 * 512 + ga);
        acc[0] = MF(a, b0, acc[0]);
        acc[1] = MF(a, b1, acc[1]);
        acc[2] = MF(a, b2, acc[2]);
        acc[3] = MF(a, b3, acc[3]);
    }
}

__device__ __forceinline__ void wpass2(
    f32x4 accR[4], f32x4 accZ[4], const u16* aS,
    const u16* __restrict__ WR, const u16* __restrict__ WZ,
    int n0, int l15, int hi)
{
    const int rx = l15 & 7;
    const u16* wpr = WR + (long)(n0 + l15) * 512 + hi * 8;
    const u16* wpz = WZ + (long)(n0 + l15) * 512 + hi * 8;
#pragma unroll 2
    for (int kc = 0; kc < 16; ++kc) {
        short8 r0 = *(const short8*)(wpr + kc * 32);
        short8 r1 = *(const short8*)(wpr + 16 * 512 + kc * 32);
        short8 r2 = *(const short8*)(wpr + 32 * 512 + kc * 32);
        short8 r3 = *(const short8*)(wpr + 48 * 512 + kc * 32);
        short8 z0 = *(const short8*)(wpz + kc * 32);
        short8 z1 = *(const short8*)(wpz + 16 * 512 + kc * 32);
        short8 z2 = *(const short8*)(wpz + 32 * 512 + kc * 32);
        short8 z3 = *(const short8*)(wpz + 48 * 512 + kc * 32);
        int ga = ((kc * 4 + hi) ^ rx) << 3;
        short8 a = *(const short8*)(aS + l15 * 512 + ga);
        accR[0] = MF(a, r0, accR[0]);
        accR[1] = MF(a, r1, accR[1]);
        accR[2] = MF(a, r2, accR[2]);
        accR[3] = MF(a, r3, accR[3]);
        accZ[0] = MF(a, z0, accZ[0]);
        accZ[1] = MF(a, z1, accZ[1]);
        accZ[2] = MF(a, z2, accZ[2]);
        accZ[3] = MF(a, z3, accZ[3]);
    }
}

#define FOR_FRAG \
    _Pragma("unroll") for (int bn = 0; bn < 4; ++bn) \
    _Pragma("unroll") for (int i = 0; i < 4; ++i)

#define ZERO4(A) \
    A[0] = f32x4{0,0,0,0}; A[1] = f32x4{0,0,0,0}; \
    A[2] = f32x4{0,0,0,0}; A[3] = f32x4{0,0,0,0};

__global__ __launch_bounds__(512, 2) void rnn_kernel(
    const u16* __restrict__ prep, const u16* __restrict__ w_t_,
    const u16* __restrict__ w_rh, const u16* __restrict__ w_zh,
    const u16* __restrict__ w_hh, float* __restrict__ out)
{
    __shared__ __align__(16) u16 hS[16 * 512];   // h state
    __shared__ __align__(16) u16 aS[16 * 512];   // ho, then rh
    const int tid = threadIdx.x;
    const int lane = tid & 63;
    const int wave = tid >> 6;
    const int l15 = lane & 15, hi = lane >> 4;
    const int n0 = wave * 64;
    const long b0 = (long)blockIdx.x * 16;

    {   // zero h state: 8192 u16 / 512 threads = 16 u16 each
        *(short8*)(hS + tid * 16) = (short8)0;
        *(short8*)(hS + tid * 16 + 8) = (short8)0;
    }
    __syncthreads();

    const u16* pbase = prep + (long)blockIdx.x * (Tsz * 4 * 8192)
                       + wave * 1024 + lane * 16;

#pragma unroll 1
    for (int t = 0; t < Tsz; ++t) {
        const u16* pt = pbase + (long)t * 4 * 8192;
        short8 po0 = ntload8(pt);
        short8 po1 = ntload8(pt + 8);

        // ---- stage A: ho = sigm(pre_o + h @ w_t^T) ----
        f32x4 accO[4]; ZERO4(accO)
        wpass1(accO, hS, w_t_, n0, l15, hi);
        float hov[4][4];
        FOR_FRAG {
            float pv = bf2f((u16)(((bn < 2) ? po0 : po1)[(bn & 1) * 4 + i]));
            float v = sigm(accO[bn][i] + pv);
            hov[bn][i] = v;
            aS[swz16(hi * 4 + i, n0 + bn * 16 + l15)] = f2bf(v);
        }
        __syncthreads();  // B1: aS(=ho) ready; hS reads done

        // ---- stage B: r,z = sigm(pre + ho @ w^T); rh = r*ho ----
        short8 pr0 = ntload8(pt + 8192);
        short8 pr1 = ntload8(pt + 8192 + 8);
        short8 pz0 = ntload8(pt + 2 * 8192);
        short8 pz1 = ntload8(pt + 2 * 8192 + 8);
        f32x4 accR[4]; ZERO4(accR)
        f32x4 accZ[4]; ZERO4(accZ)
        wpass2(accR, accZ, aS, w_rh, w_zh, n0, l15, hi);
        float zv[4][4], rhv[4][4];
        FOR_FRAG {
            float pzv = bf2f((u16)(((bn < 2) ? pz0 : pz1)[(bn & 1) * 4 + i]));
            float prv = bf2f((u16)(((bn < 2) ? pr0 : pr1)[(bn & 1) * 4 + i]));
            zv[bn][i] = sigm(accZ[bn][i] + pzv);
            rhv[bn][i] = sigm(accR[bn][i] + prv) * hov[bn][i];
        }
        __syncthreads();  // B2: all waves done READING aS(=ho)
        FOR_FRAG {
            aS[swz16(hi * 4 + i, n0 + bn * 16 + l15)] = f2bf(rhv[bn][i]);
        }
        __syncthreads();  // B3: aS(=rh) ready

        // ---- stage C: h~ = tanh(pre_h + rh @ w_hh^T); h = (1-z)ho + z h~ ----
        short8 ph0 = ntload8(pt + 3 * 8192);
        short8 ph1 = ntload8(pt + 3 * 8192 + 8);
        f32x4 accH[4]; ZERO4(accH)
        wpass1(accH, aS, w_hh, n0, l15, hi);
        FOR_FRAG {
            int row = hi * 4 + i, col = n0 + bn * 16 + l15;
            float phv = bf2f((u16)(((bn < 2) ? ph0 : ph1)[(bn & 1) * 4 + i]));
            float htl = tanhf(accH[bn][i] + phv);
            float z = zv[bn][i];
            float hn = (1.0f - z) * hov[bn][i] + z * htl;
            __builtin_nontemporal_store(
                hn, &out[((b0 + row) * Tsz + t) * (long)Hsz + col]);
            hS[swz16(row, col)] = f2bf(hn);
        }
        __syncthreads();  // B4: hS ready; aS(=rh) reads done
    }
}

extern "C" void kernel_launch(void* const* d_in, const int* in_sizes, int n_in,
                              void* d_out, int out_size, void* d_ws, size_t ws_size,
                              hipStream_t stream) {
    const float* x_f    = (const float*)d_in[0];
    const float* xw_f   = (const float*)d_in[1];
    const float* w_rx_f = (const float*)d_in[2];
    const float* w_rh_f = (const float*)d_in[3];
    const float* w_re_f = (const float*)d_in[4];
    const float* b_r    = (const float*)d_in[5];
    const float* w_zx_f = (const float*)d_in[6];
    const float* w_zh_f = (const float*)d_in[7];
    const float* w_ze_f = (const float*)d_in[8];
    const float* b_z    = (const float*)d_in[9];
    const float* w_hx_f = (const float*)d_in[10];
    const float* w_hh_f = (const float*)d_in[11];
    const float* b_h    = (const float*)d_in[12];
    const float* w_d_f  = (const float*)d_in[13];
    const float* w_w_f  = (const float*)d_in[14];
    const float* w_m_f  = (const float*)d_in[15];
    const float* w_t_f  = (const float*)d_in[16];
    const float* w_e_f  = (const float*)d_in[17];
    const float* b_e    = (const float*)d_in[18];
    float* out = (float*)d_out;

    char* ws = (char*)d_ws;
    size_t off = 0;
    auto alloc = [&](size_t bytes) {
        size_t o = off; off = (off + bytes + 255) & ~(size_t)255; return o;
    };
    const size_t nx  = (size_t)Msz * Isz;
    const size_t nxw = (size_t)Msz * Wsz;

    u16* x_bf  = (u16*)(ws + alloc(nx * 2));
    u16* xw_bf = (u16*)(ws + alloc(nxw * 2));
    u16* w_rx  = (u16*)(ws + alloc(Hsz * Isz * 2));
    u16* w_rh  = (u16*)(ws + alloc(Hsz * Hsz * 2));
    u16* w_re  = (u16*)(ws + alloc(Hsz * Hsz * 2));
    u16* w_zx  = (u16*)(ws + alloc(Hsz * Isz * 2));
    u16* w_zh  = (u16*)(ws + alloc(Hsz * Hsz * 2));
    u16* w_ze  = (u16*)(ws + alloc(Hsz * Hsz * 2));
    u16* w_hx  = (u16*)(ws + alloc(Hsz * Isz * 2));
    u16* w_hh  = (u16*)(ws + alloc(Hsz * Hsz * 2));
    u16* w_d   = (u16*)(ws + alloc(Hsz * Isz * 2));
    u16* w_w   = (u16*)(ws + alloc(Hsz * Isz * 2));
    u16* w_m   = (u16*)(ws + alloc(Hsz * Isz * 2));
    u16* w_t   = (u16*)(ws + alloc(Hsz * Hsz * 2));
    u16* w_e   = (u16*)(ws + alloc(Hsz * Wsz * 2));
    u16* e_bf  = (u16*)(ws + alloc((size_t)Msz * Hsz * 2));   // 96 MB [b*T+t]
    u16* prep  = (u16*)(ws + alloc((size_t)Msz * 2048 * 2));  // 384 MB permuted
    u16* zerobuf = (u16*)(ws + alloc(256));

    convert_big<<<(int)(nx / 1024), 256, 0, stream>>>(x_f, x_bf, (int)nx);
    convert_big<<<(int)(nxw / 1024), 256, 0, stream>>>(xw_f, xw_bf, (int)nxw);
    ConvTab tab;
    tab.d[0]  = { w_rx_f, w_rx, Hsz * Isz };
    tab.d[1]  = { w_rh_f, w_rh, Hsz * Hsz };
    tab.d[2]  = { w_re_f, w_re, Hsz * Hsz };
    tab.d[3]  = { w_zx_f, w_zx, Hsz * Isz };
    tab.d[4]  = { w_zh_f, w_zh, Hsz * Hsz };
    tab.d[5]  = { w_ze_f, w_ze, Hsz * Hsz };
    tab.d[6]  = { w_hx_f, w_hx, Hsz * Isz };
    tab.d[7]  = { w_hh_f, w_hh, Hsz * Hsz };
    tab.d[8]  = { w_d_f,  w_d,  Hsz * Isz };
    tab.d[9]  = { w_w_f,  w_w,  Hsz * Isz };
    tab.d[10] = { w_m_f,  w_m,  Hsz * Isz };
    tab.d[11] = { w_t_f,  w_t,  Hsz * Hsz };
    tab.d[12] = { w_e_f,  w_e,  Hsz * Wsz };
    convert_many<<<dim3(256, 13), 256, 0, stream>>>(tab);
    hipMemsetAsync(zerobuf, 0, 256, stream);

    // e = sigmoid(xw @ w_e^T + b_e)  [98304 x 512], layout [b*T+t]
    ekernel<<<dim3(Msz / 64, Hsz / 64), 256, 0, stream>>>(xw_bf, w_e, b_e, e_bf);

    // pre-pass: all input-only projections, frag-permuted output
    prepass_kernel<<<dim3(Msz / 128, 16), 256, 0, stream>>>(
        x_bf, e_bf, w_d, w_w, w_m, w_rx, w_re, w_zx, w_ze, w_hx,
        b_r, b_z, b_h, zerobuf, prep);

    // persistent recurrence: whole T-loop in one kernel, 256 blocks (all CUs)
    rnn_kernel<<<Bsz / 16, 512, 0, stream>>>(prep, w_t, w_rh, w_zh, w_hh, out);
}